// Round 5
// baseline (2136.791 us; speedup 1.0000x reference)
//
#include <hip/hip_runtime.h>

// WeatherModel: ConvLSTM encoder-decoder with attention.
// Big ConvLSTM cells + attention e-conv via bf16 MFMA implicit GEMM.
// B=4, T_IN=10, T_OUT=5, D=5, M=N=96, H1=64, ATTN=32, SEL=0.

#define PIX  9216
#define NB   4
#define TIN  10
#define TOUT 5
#define ND   5
#define HID  64

typedef __attribute__((ext_vector_type(8))) short bf16x8;
typedef __attribute__((ext_vector_type(4))) float f32x4;

__device__ __forceinline__ float sigmf_(float x) { return 1.0f / (1.0f + __expf(-x)); }
__device__ __forceinline__ float tanhf_(float x) { return 1.0f - 2.0f / (__expf(2.0f * x) + 1.0f); }
__device__ __forceinline__ unsigned short f2bf(float f) {
    unsigned u = __float_as_uint(f);
    unsigned r = u + 0x7FFFu + ((u >> 16) & 1u);
    return (unsigned short)(r >> 16);
}
__device__ __forceinline__ float bf2f(unsigned short u) {
    return __uint_as_float(((unsigned)u) << 16);
}
// monotone float<->uint map for atomicMax-based global max
__device__ __forceinline__ unsigned fmap_(float f) {
    unsigned u = __float_as_uint(f);
    return (u & 0x80000000u) ? ~u : (u | 0x80000000u);
}
__device__ __forceinline__ float funmap_(unsigned v) {
    return __uint_as_float((v & 0x80000000u) ? (v ^ 0x80000000u) : ~v);
}

// ---------------------------------------------------------------------------
// Big ConvLSTM cell, implicit-GEMM MFMA.
// Wave wv owns oc sub-block wv*16 within EACH gate (all 4 gates in-register).
// Double-buffered staging, 1 barrier per cin-chunk. Grid (2,96,NB).
// ---------------------------------------------------------------------------
template <int NCH>
__global__ void __launch_bounds__(256, 3)
cell64_mfma(const unsigned short* __restrict__ inP,
            const unsigned short* __restrict__ wP,
            const float* __restrict__ bias,
            const float* cprev, float* cout,
            unsigned short* __restrict__ d1, int d1_coff, int d1_ncg,
            unsigned short* __restrict__ d2, int d2_coff, int d2_ncg)
{
    __shared__ __align__(16) char smem[2][9600];   // [pr 150][4 slots][16B], dbuf
    const int lane = threadIdx.x;
    const int wv   = threadIdx.y;
    const int tid  = wv * 64 + lane;
    const int xh = blockIdx.x, y = blockIdx.y, b = blockIdx.z;
    const int x0 = xh * 48;
    const int l15 = lane & 15, l4 = lane >> 4;
    const int NCG = NCH * 4;

    const int scg  = tid & 3;
    const int spr0 = tid >> 2;

    auto stage = [&](char* buf, int cc) {
#pragma unroll
        for (int i = 0; i < 3; ++i) {
            int pr = spr0 + i * 64;
            if (i == 2 && pr >= 150) break;
            int r = (pr >= 100) ? 2 : (pr >= 50 ? 1 : 0);
            int p = pr - r * 50;
            int gy = y - 1 + r, gx = x0 - 1 + p;
            uint4 v = make_uint4(0u, 0u, 0u, 0u);
            if ((unsigned)gy < 96u && (unsigned)gx < 96u)
                v = *(const uint4*)(inP + (((size_t)(b * NCG + cc * 4 + scg) * 9216
                                            + gy * 96 + gx) << 3));
            int slot = scg ^ ((p >> 1) & 3);
            *(uint4*)(buf + pr * 64 + slot * 16) = v;
        }
    };

    f32x4 acc[4][3] = {};

    stage((char*)smem[0], 0);
    for (int cc = 0; cc < NCH; ++cc) {
        __syncthreads();
        if (cc + 1 < NCH) stage((char*)smem[(cc + 1) & 1], cc + 1);
        const char* buf = (const char*)smem[cc & 1];
#pragma unroll
        for (int ky = 0; ky < 3; ++ky) {
#pragma unroll
            for (int kx = 0; kx < 3; ++kx) {
                const int tap = ky * 3 + kx;
                bf16x8 af[4];
#pragma unroll
                for (int g = 0; g < 4; ++g)
                    af[g] = *(const bf16x8*)(wP
                        + ((size_t)(tap * NCH + cc) * 256 + g * 64 + wv * 16 + l15) * 32 + l4 * 8);
                bf16x8 bk[3];
#pragma unroll
                for (int k = 0; k < 3; ++k) {
                    int p = k * 16 + kx + l15;
                    int slot = l4 ^ ((p >> 1) & 3);
                    bk[k] = *(const bf16x8*)(buf + (ky * 50 + p) * 64 + slot * 16);
                }
#pragma unroll
                for (int g = 0; g < 4; ++g)
#pragma unroll
                    for (int k = 0; k < 3; ++k)
                        acc[g][k] = __builtin_amdgcn_mfma_f32_16x16x32_bf16(
                            af[g], bk[k], acc[g][k], 0, 0, 0);
            }
        }
    }

#pragma unroll
    for (int r = 0; r < 4; ++r) {
        int hc = wv * 16 + l4 * 4 + r;
        float bi = bias[hc], bff = bias[64 + hc];
        float bo = bias[128 + hc], bg = bias[192 + hc];
#pragma unroll
        for (int k = 0; k < 3; ++k) {
            int px = k * 16 + l15;
            int gpix = y * 96 + x0 + px;
            float ii = sigmf_(acc[0][k][r] + bi);
            float ff = sigmf_(acc[1][k][r] + bff);
            float oo = sigmf_(acc[2][k][r] + bo);
            float gg = tanhf_(acc[3][k][r] + bg);
            int cidx = (b * HID + hc) * 9216 + gpix;
            float cn = ff * cprev[cidx] + ii * gg;
            cout[cidx] = cn;
            unsigned short hb = f2bf(oo * tanhf_(cn));
            int ch1 = d1_coff + hc;
            d1[((size_t)(b * d1_ncg + (ch1 >> 3)) * 9216 + gpix) * 8 + (ch1 & 7)] = hb;
            if (d2) {
                int ch2 = d2_coff + hc;
                d2[((size_t)(b * d2_ncg + (ch2 >> 3)) * 9216 + gpix) * 8 + (ch2 & 7)] = hb;
            }
        }
    }
}

__global__ void wpack_kernel(const float* __restrict__ w, unsigned short* __restrict__ wp,
                             int WCIN, int NCH, int coff, int climit)
{
    int idx = blockIdx.x * 256 + threadIdx.x;
    int total = 9 * NCH * 256 * 32;
    if (idx >= total) return;
    int k = idx & 31;
    int oc = (idx >> 5) & 255;
    int rest = idx >> 13;
    int cc = rest % NCH, tap = rest / NCH;
    int c = cc * 32 + k;
    float v = 0.0f;
    if (c < climit) v = w[(oc * WCIN + (c + coff)) * 9 + tap];
    wp[idx] = f2bf(v);
}

// ---------------------------------------------------------------------------
// Small ConvLSTM cell (hidden=1) on 5-ch input: thread per (px, gate).
// ---------------------------------------------------------------------------
__global__ void __launch_bounds__(256)
small_cell5(const float* __restrict__ xs_t,
            const float* __restrict__ hprev, const float* cprev,
            const float* __restrict__ w, const float* __restrict__ bias,
            float* __restrict__ hout, float* cout,
            unsigned short* __restrict__ pk, int ncg)
{
    __shared__ float z[4][64];
    const int pxl = threadIdx.x & 63, gate = threadIdx.x >> 6;
    const int p = blockIdx.x * 64 + pxl, bb = blockIdx.y;
    const int y = p / 96, x = p - y * 96;
    float acc = bias[gate];
#pragma unroll
    for (int cin = 0; cin < 6; ++cin) {
        const float* src = (cin < 5) ? (xs_t + (bb * TIN * ND + cin) * PIX)
                                     : (hprev + bb * PIX);
        const float* wp = w + (gate * 6 + cin) * 9;
#pragma unroll
        for (int ky = 0; ky < 3; ++ky) {
            int gy = y + ky - 1;
            if ((unsigned)gy >= 96u) continue;
#pragma unroll
            for (int kx = 0; kx < 3; ++kx) {
                int gx = x + kx - 1;
                if ((unsigned)gx >= 96u) continue;
                acc = fmaf(wp[ky * 3 + kx], src[gy * 96 + gx], acc);
            }
        }
    }
    z[gate][pxl] = acc;
    __syncthreads();
    if (threadIdx.x < 64) {
        int pp = blockIdx.x * 64 + threadIdx.x;
        int idx = bb * PIX + pp;
        float cn = sigmf_(z[1][threadIdx.x]) * cprev[idx]
                 + sigmf_(z[0][threadIdx.x]) * tanhf_(z[3][threadIdx.x]);
        cout[idx] = cn;
        float h = sigmf_(z[2][threadIdx.x]) * tanhf_(cn);
        hout[idx] = h;
        pk[((size_t)(bb * ncg) * 9216 + pp) * 8] = f2bf(h);
    }
}

// ---------------------------------------------------------------------------
// dec2 layer (64 packed bf16 cin + 1 fp32 hprev cin -> 4 gates).
// LDS-staged: tile 32x8 px, halo 34x10 x 64ch bf16 (43.5 KB, XOR slots).
// Thread = 1 px, computes all 4 gates; weights uniform float4 (scalar pipe).
// Grid (3, 12, NB).
// ---------------------------------------------------------------------------
__global__ void __launch_bounds__(256)
small_cell64(const unsigned short* __restrict__ xin, int ncg, int cgbase,
             const float* __restrict__ hprev, const float* cprev,
             const float* __restrict__ w4,      // [65*9][4] gate-last
             const float* __restrict__ bias,
             float* __restrict__ hout, float* cout)
{
    __shared__ __align__(16) char stg[10 * 34 * 128];
    const int tid = threadIdx.x;
    const int x0 = blockIdx.x * 32, y0 = blockIdx.y * 8, bb = blockIdx.z;

    for (int i = tid; i < 2720; i += 256) {        // 80 (r,cg) x 34 p
        int p = i % 34;
        int rc = i / 34;
        int cg = rc & 7, r = rc >> 3;
        int gy = y0 - 1 + r, gx = x0 - 1 + p;
        uint4 v = make_uint4(0u, 0u, 0u, 0u);
        if ((unsigned)gy < 96u && (unsigned)gx < 96u)
            v = *(const uint4*)(xin + ((size_t)(bb * ncg + cgbase + cg) * 9216
                                       + gy * 96 + gx) * 8);
        *(uint4*)(stg + ((r * 34 + p) * 8 + (cg ^ (p & 7))) * 16) = v;
    }
    __syncthreads();

    const int x = tid & 31, y = tid >> 5;          // 32 x 8
    float aI = bias[0], aF = bias[1], aO = bias[2], aG = bias[3];
#pragma unroll
    for (int ky = 0; ky < 3; ++ky) {
#pragma unroll
        for (int kx = 0; kx < 3; ++kx) {
            const int tap = ky * 3 + kx;
            const int xc = x + kx;
            const char* bp = stg + ((y + ky) * 34 + xc) * 128;
            const int sx = xc & 7;
#pragma unroll
            for (int cg = 0; cg < 8; ++cg) {
                const uint4 v = *(const uint4*)(bp + ((cg ^ sx) << 4));
#pragma unroll
                for (int jj = 0; jj < 4; ++jj) {
                    unsigned u = (&v.x)[jj];
                    float lo = __uint_as_float(u << 16);
                    float hi = __uint_as_float(u & 0xFFFF0000u);
                    const float4 wl = *(const float4*)(w4 + ((cg * 8 + jj * 2) * 9 + tap) * 4);
                    const float4 wh = *(const float4*)(w4 + ((cg * 8 + jj * 2 + 1) * 9 + tap) * 4);
                    aI = fmaf(wl.x, lo, aI); aF = fmaf(wl.y, lo, aF);
                    aO = fmaf(wl.z, lo, aO); aG = fmaf(wl.w, lo, aG);
                    aI = fmaf(wh.x, hi, aI); aF = fmaf(wh.y, hi, aF);
                    aO = fmaf(wh.z, hi, aO); aG = fmaf(wh.w, hi, aG);
                }
            }
            int gy = y0 + y + ky - 1, gx = x0 + x + kx - 1;
            float hv = ((unsigned)gy < 96u && (unsigned)gx < 96u)
                       ? hprev[bb * PIX + gy * 96 + gx] : 0.0f;
            const float4 w64 = *(const float4*)(w4 + (64 * 9 + tap) * 4);
            aI = fmaf(w64.x, hv, aI); aF = fmaf(w64.y, hv, aF);
            aO = fmaf(w64.z, hv, aO); aG = fmaf(w64.w, hv, aG);
        }
    }
    int idx = bb * PIX + (y0 + y) * 96 + x0 + x;
    float cn = sigmf_(aF) * cprev[idx] + sigmf_(aI) * tanhf_(aG);
    cout[idx] = cn;
    hout[idx] = sigmf_(aO) * tanhf_(cn);
}

// pack dec_w2 [4 oc][65 cin][9] -> [65*9][4]
__global__ void wd2pack_kernel(const float* __restrict__ w, float* __restrict__ w4)
{
    int i = blockIdx.x * 256 + threadIdx.x;
    if (i >= 585 * 4) return;
    int g = i & 3, ct = i >> 2;
    int cin = ct / 9, tap = ct - cin * 9;
    w4[ct * 4 + g] = w[(g * 65 + cin) * 9 + tap];
}

// ---------------------------------------------------------------------------
// Attention, MFMA edition.
// ---------------------------------------------------------------------------
__global__ void pack_wi_kernel(const float* __restrict__ wi, unsigned short* __restrict__ wiP)
{
    int idx = blockIdx.x * 256 + threadIdx.x;
    if (idx >= 5120) return;
    int kl = idx & 31, oc = (idx >> 5) & 31, j = idx >> 10;
    int tappos = kl >> 4, ch = kl & 15;
    int tap = 2 * j + tappos;
    float v = 0.0f;
    if (tap < 9 && ch < 10) v = wi[(oc * TIN + ch) * 9 + tap];
    wiP[idx] = f2bf(v);
}

__global__ void hidE_kernel(const float* __restrict__ h0, const float* __restrict__ c0,
                            const float* __restrict__ wh, const float* __restrict__ bh,
                            const float* __restrict__ bi, float* __restrict__ heP)
{
    int idx = blockIdx.x * 256 + threadIdx.x;
    int bb = blockIdx.y;
    int cg = idx & 3, p = idx >> 2;
    int y = p / 96, x = p - y * 96;
    float acc[8];
#pragma unroll
    for (int j = 0; j < 8; ++j) acc[j] = bi[cg * 8 + j] + bh[cg * 8 + j];
#pragma unroll
    for (int cin = 0; cin < 2; ++cin) {
        const float* src = (cin == 0 ? h0 : c0) + bb * PIX;
#pragma unroll
        for (int ky = 0; ky < 3; ++ky) {
            int gy = y + ky - 1;
            if ((unsigned)gy >= 96u) continue;
#pragma unroll
            for (int kx = 0; kx < 3; ++kx) {
                int gx = x + kx - 1;
                if ((unsigned)gx >= 96u) continue;
                float v = src[gy * 96 + gx];
#pragma unroll
                for (int j = 0; j < 8; ++j)
                    acc[j] = fmaf(wh[((cg * 8 + j) * 2 + cin) * 9 + ky * 3 + kx], v, acc[j]);
            }
        }
    }
    float* dst = heP + ((size_t)(bb * PIX) + p) * 32 + cg * 8;
    *(float4*)dst = make_float4(acc[0], acc[1], acc[2], acc[3]);
    *(float4*)(dst + 4) = make_float4(acc[4], acc[5], acc[6], acc[7]);
}

__global__ void __launch_bounds__(256)
attn_e_mfma(const unsigned short* __restrict__ xsp, const unsigned short* __restrict__ wiP,
            const float* __restrict__ heP, unsigned short* __restrict__ eP)
{
    const int lane = threadIdx.x, wvid = threadIdx.y;
    const int tile = blockIdx.x, k = blockIdx.y, bb = blockIdx.z;
    const int l15 = lane & 15, l4 = lane >> 4;

    bf16x8 af[5][2];
#pragma unroll
    for (int j = 0; j < 5; ++j)
#pragma unroll
        for (int m = 0; m < 2; ++m)
            af[j][m] = *(const bf16x8*)(wiP + ((size_t)(j * 32 + m * 16 + l15)) * 32 + l4 * 8);

    const unsigned short* xb = xsp + (size_t)(bb * ND + k) * PIX * 16;
    const int p0 = tile * 256 + wvid * 64;

    f32x4 acc[4][2] = {};
#pragma unroll
    for (int nf = 0; nf < 4; ++nf) {
        int p = p0 + nf * 16 + l15;
        int y = p / 96, x = p - y * 96;
#pragma unroll
        for (int j = 0; j < 5; ++j) {
            int tp = 2 * j + (l4 >> 1);
            bf16x8 bk = { 0, 0, 0, 0, 0, 0, 0, 0 };
            if (tp < 9) {
                int gy = y + tp / 3 - 1, gx = x + tp % 3 - 1;
                if ((unsigned)gy < 96u && (unsigned)gx < 96u)
                    bk = *(const bf16x8*)(xb + ((size_t)(gy * 96 + gx)) * 16 + (l4 & 1) * 8);
            }
            acc[nf][0] = __builtin_amdgcn_mfma_f32_16x16x32_bf16(af[j][0], bk, acc[nf][0], 0, 0, 0);
            acc[nf][1] = __builtin_amdgcn_mfma_f32_16x16x32_bf16(af[j][1], bk, acc[nf][1], 0, 0, 0);
        }
    }

#pragma unroll
    for (int nf = 0; nf < 4; ++nf) {
        int p = p0 + nf * 16 + l15;
#pragma unroll
        for (int m = 0; m < 2; ++m) {
            const float4 he = *(const float4*)(heP + ((size_t)(bb * PIX) + p) * 32 + m * 16 + l4 * 4);
            ushort4 o;
            o.x = f2bf(tanhf_(acc[nf][m][0] + he.x));
            o.y = f2bf(tanhf_(acc[nf][m][1] + he.y));
            o.z = f2bf(tanhf_(acc[nf][m][2] + he.z));
            o.w = f2bf(tanhf_(acc[nf][m][3] + he.w));
            *(ushort4*)(eP + ((size_t)(bb * ND + k) * PIX + p) * 32 + m * 16 + l4 * 4) = o;
        }
    }
}

__global__ void __launch_bounds__(256)
attn_alpha(const unsigned short* __restrict__ eP, const float* __restrict__ wvv,
           const float* __restrict__ bv, float* __restrict__ alpha,
           unsigned* __restrict__ msl)
{
    int p = blockIdx.x * 256 + threadIdx.x;
    int k = blockIdx.y, bb = blockIdx.z;
    int y = p / 96, x = p - y * 96;
    const unsigned short* eb = eP + (size_t)(bb * ND + k) * PIX * 32;
    float acc = bv[0];
#pragma unroll
    for (int ky = 0; ky < 3; ++ky) {
        int gy = y + ky - 1;
        if ((unsigned)gy >= 96u) continue;
#pragma unroll
        for (int kx = 0; kx < 3; ++kx) {
            int gx = x + kx - 1;
            if ((unsigned)gx >= 96u) continue;
            int tap = ky * 3 + kx;
            const unsigned short* ee = eb + ((size_t)(gy * 96 + gx)) * 32;
#pragma unroll
            for (int cg = 0; cg < 4; ++cg) {
                bf16x8 ev = *(const bf16x8*)(ee + cg * 8);
#pragma unroll
                for (int jj = 0; jj < 8; ++jj)
                    acc = fmaf(wvv[(cg * 8 + jj) * 9 + tap], bf2f((unsigned short)ev[jj]), acc);
            }
        }
    }
    alpha[(size_t)(bb * ND + k) * PIX + p] = acc;

    __shared__ float s[256];
    s[threadIdx.x] = acc;
    __syncthreads();
    for (int st = 128; st > 0; st >>= 1) {
        if (threadIdx.x < st) s[threadIdx.x] = fmaxf(s[threadIdx.x], s[threadIdx.x + st]);
        __syncthreads();
    }
    if (threadIdx.x == 0) atomicMax(msl, fmap_(s[0]));
}

__global__ void scale_pack_kernel(float* __restrict__ xs, unsigned short* __restrict__ xsp,
                                  const float* __restrict__ alpha,
                                  const unsigned* __restrict__ msl)
{
    int idx = blockIdx.x * 256 + threadIdx.x;
    int p = idx % PIX;
    int q = idx / PIX;
    int d = q % ND, bb = q / ND;
    float mval = funmap_(msl[0]);
    float w = __expf(alpha[idx] - mval);
    unsigned short tmp[16];
#pragma unroll
    for (int t = 0; t < TIN; ++t) {
        size_t xi = ((size_t)(bb * TIN + t) * ND + d) * PIX + p;
        float v = xs[xi] * w;
        xs[xi] = v;
        tmp[t] = f2bf(v);
    }
#pragma unroll
    for (int t = TIN; t < 16; ++t) tmp[t] = 0;
    uint4* dst = (uint4*)(xsp + (size_t)idx * 16);
    dst[0] = *(uint4*)&tmp[0];
    dst[1] = *(uint4*)&tmp[8];
}

__global__ void pack_xsp_kernel(const float* __restrict__ x, unsigned short* __restrict__ xsp)
{
    int idx = blockIdx.x * 256 + threadIdx.x;
    int p = idx % PIX;
    int q = idx / PIX;
    int d = q % ND, bb = q / ND;
    unsigned short tmp[16];
#pragma unroll
    for (int t = 0; t < TIN; ++t)
        tmp[t] = f2bf(x[((size_t)(bb * TIN + t) * ND + d) * PIX + p]);
#pragma unroll
    for (int t = TIN; t < 16; ++t) tmp[t] = 0;
    uint4* dst = (uint4*)(xsp + (size_t)idx * 16);
    dst[0] = *(uint4*)&tmp[0];
    dst[1] = *(uint4*)&tmp[8];
}

// ---------------------------------------------------------------------------
__global__ void tcnn_kernel(const float* __restrict__ yprev, const float* __restrict__ hl,
                            const float* __restrict__ tw, const float* __restrict__ tb,
                            float* __restrict__ ynext, float* __restrict__ hcarry,
                            float* __restrict__ outp)
{
    int p = blockIdx.x * 256 + threadIdx.x;
    int bb = blockIdx.y;
    float acc = tb[0];
#pragma unroll
    for (int cc = 0; cc < TIN; ++cc)
        acc = fmaf(tw[cc], yprev[(bb * TIN + cc) * PIX + p], acc);
    float hv = hl[bb * PIX + p];
    acc = fmaf(tw[TIN], hv, acc);
    float o = fmaxf(acc, 0.0f);
    outp[bb * TOUT * PIX + p] = o;
#pragma unroll
    for (int cc = 0; cc < TIN - 1; ++cc)
        ynext[(bb * TIN + cc) * PIX + p] = yprev[(bb * TIN + cc + 1) * PIX + p];
    ynext[(bb * TIN + 9) * PIX + p] = hv;
    hcarry[bb * PIX + p] = o;
}

__global__ void slice_y_kernel(const float* __restrict__ x, float* __restrict__ yp)
{
    int idx = blockIdx.x * 256 + threadIdx.x;
    int p = idx % PIX;
    int q = idx / PIX;
    yp[idx] = x[(size_t)(q * ND + 0) * PIX + p];
}

// ---------------------------------------------------------------------------
extern "C" void kernel_launch(void* const* d_in, const int* in_sizes, int n_in,
                              void* d_out, int out_size, void* d_ws, size_t ws_size,
                              hipStream_t stream)
{
    const float* x       = (const float*)d_in[0];
    const float* enc_w0  = (const float*)d_in[1];
    const float* enc_b0  = (const float*)d_in[2];
    const float* enc_w1  = (const float*)d_in[3];
    const float* enc_b1  = (const float*)d_in[4];
    const float* enc_w2  = (const float*)d_in[5];
    const float* enc_b2  = (const float*)d_in[6];
    const float* dec_w0  = (const float*)d_in[7];
    const float* dec_b0  = (const float*)d_in[8];
    const float* dec_w1  = (const float*)d_in[9];
    const float* dec_b1  = (const float*)d_in[10];
    const float* dec_w2  = (const float*)d_in[11];
    const float* dec_b2  = (const float*)d_in[12];
    const float* attn_wi = (const float*)d_in[13];
    const float* attn_bi = (const float*)d_in[14];
    const float* attn_wh = (const float*)d_in[15];
    const float* attn_bh = (const float*)d_in[16];
    const float* attn_wv = (const float*)d_in[17];
    const float* attn_bv = (const float*)d_in[18];
    const float* tcnn_w  = (const float*)d_in[19];
    const float* tcnn_b  = (const float*)d_in[20];
    float* out = (float*)d_out;

    char* cur = (char*)d_ws;
    auto alloc = [&](size_t bytes) { char* p = cur; cur += (bytes + 255) & ~(size_t)255; return p; };
    float* xs   = (float*)alloc((size_t)NB * TIN * ND * PIX * 4);
    float* h0a  = (float*)alloc(NB * PIX * 4);
    float* h0b  = (float*)alloc(NB * PIX * 4);
    float* c0   = (float*)alloc(NB * PIX * 4);
    float* hl   = (float*)alloc(NB * PIX * 4);
    float* c1   = (float*)alloc((size_t)NB * HID * PIX * 4);
    float* c2   = (float*)alloc((size_t)NB * HID * PIX * 4);
    float* alp  = (float*)alloc((size_t)NB * ND * PIX * 4);
    float* ypa  = (float*)alloc((size_t)NB * TIN * PIX * 4);
    float* ypb  = (float*)alloc((size_t)NB * TIN * PIX * 4);
    unsigned* mslot = (unsigned*)alloc(256);
    float* wd2p = (float*)alloc(585 * 4 * 4);
    const size_t IN1_B = (size_t)NB * 12 * PIX * 8 * 2;
    const size_t IN2_B = (size_t)NB * 16 * PIX * 8 * 2;
    unsigned short* In1a = (unsigned short*)alloc(IN1_B);
    unsigned short* In1b = (unsigned short*)alloc(IN1_B);
    unsigned short* In2a = (unsigned short*)alloc(IN2_B);
    unsigned short* In2b = (unsigned short*)alloc(IN2_B);
    unsigned short* wpe1 = (unsigned short*)alloc((size_t)9 * 3 * 256 * 32 * 2);
    unsigned short* wpe2 = (unsigned short*)alloc((size_t)9 * 4 * 256 * 32 * 2);
    unsigned short* wpd0 = (unsigned short*)alloc((size_t)9 * 2 * 256 * 32 * 2);
    unsigned short* wpd1 = (unsigned short*)alloc((size_t)9 * 4 * 256 * 32 * 2);
    unsigned short* xsp  = (unsigned short*)alloc((size_t)NB * ND * PIX * 16 * 2);
    unsigned short* wiP  = (unsigned short*)alloc(5120 * 2);
    float* heP = (float*)alloc((size_t)NB * PIX * 32 * 4);
    unsigned short* eP = (unsigned short*)alloc((size_t)NB * ND * PIX * 32 * 2);

    hipMemcpyAsync(xs, x, (size_t)NB * TIN * ND * PIX * 4, hipMemcpyDeviceToDevice, stream);
    hipMemsetAsync(h0a, 0, NB * PIX * 4, stream);
    hipMemsetAsync(c0,  0, NB * PIX * 4, stream);
    hipMemsetAsync(c1,  0, (size_t)NB * HID * PIX * 4, stream);
    hipMemsetAsync(c2,  0, (size_t)NB * HID * PIX * 4, stream);
    hipMemsetAsync(In1a, 0, IN1_B, stream);
    hipMemsetAsync(In1b, 0, IN1_B, stream);
    hipMemsetAsync(In2a, 0, IN2_B, stream);
    hipMemsetAsync(In2b, 0, IN2_B, stream);
    hipMemsetAsync(mslot, 0, 256, stream);
    slice_y_kernel<<<dim3(1440), 256, 0, stream>>>(x, ypa);

    wpack_kernel<<<dim3(864),  256, 0, stream>>>(enc_w1, wpe1, 65, 3, 0, 65);
    wpack_kernel<<<dim3(1152), 256, 0, stream>>>(enc_w2, wpe2, 128, 4, 0, 128);
    wpack_kernel<<<dim3(576),  256, 0, stream>>>(dec_w0, wpd0, 65, 2, 1, 64);
    wpack_kernel<<<dim3(1152), 256, 0, stream>>>(dec_w1, wpd1, 128, 4, 0, 128);
    wd2pack_kernel<<<dim3(10), 256, 0, stream>>>(dec_w2, wd2p);
    pack_wi_kernel<<<dim3(20), 256, 0, stream>>>(attn_wi, wiP);
    pack_xsp_kernel<<<dim3(720), 256, 0, stream>>>(x, xsp);

    dim3 big_grid(2, 96, NB), big_block(64, 4);
    dim3 attn_block(64, 4);
    float *h0 = h0a, *h0n = h0b;
    unsigned short *i1c = In1a, *i1n = In1b, *i2c = In2a, *i2n = In2b;

    // ---------------- encoder ----------------
    for (int t = 0; t < TIN; ++t) {
        hidE_kernel<<<dim3(144, NB), 256, 0, stream>>>(h0, c0, attn_wh, attn_bh, attn_bi, heP);
        attn_e_mfma<<<dim3(36, ND, NB), attn_block, 0, stream>>>(xsp, wiP, heP, eP);
        attn_alpha<<<dim3(36, ND, NB), 256, 0, stream>>>(eP, attn_wv, attn_bv, alp, mslot + t);
        scale_pack_kernel<<<dim3(720), 256, 0, stream>>>(xs, xsp, alp, mslot + t);

        small_cell5<<<dim3(144, NB), 256, 0, stream>>>(xs + (size_t)t * ND * PIX, h0, c0,
                                                       enc_w0, enc_b0, h0n, c0, i1c, 12);
        { float* tmp = h0; h0 = h0n; h0n = tmp; }

        unsigned short* e1d1 = (t < TIN - 1) ? i1n : In2a;
        int e1o = (t < TIN - 1) ? 1 : 64;
        int e1n = (t < TIN - 1) ? 12 : 16;
        cell64_mfma<3><<<big_grid, big_block, 0, stream>>>(i1c, wpe1, enc_b1, c1, c1,
                                                           e1d1, e1o, e1n, i2c, 0, 16);
        unsigned short* e2d1 = (t < TIN - 1) ? i2n : In1a;
        int e2o = (t < TIN - 1) ? 64 : 0;
        int e2n = (t < TIN - 1) ? 16 : 8;
        cell64_mfma<4><<<big_grid, big_block, 0, stream>>>(i2c, wpe2, enc_b2, c2, c2,
                                                           e2d1, e2o, e2n, nullptr, 0, 0);
        { unsigned short* tmp = i1c; i1c = i1n; i1n = tmp; }
        { unsigned short* tmp = i2c; i2c = i2n; i2n = tmp; }
    }

    // ---------------- decoder ----------------
    unsigned short *d0c = In1a, *d0n = In1b, *d1c = In2a, *d1n = In2b;
    float *yp = ypa, *ypn = ypb, *hc = h0, *hcn = h0n;
    for (int t = 0; t < TOUT; ++t) {
        cell64_mfma<2><<<big_grid, big_block, 0, stream>>>(d0c, wpd0, dec_b0, c2, c2,
                                                           d0n, 0, 8, d1c, 0, 16);
        cell64_mfma<4><<<big_grid, big_block, 0, stream>>>(d1c, wpd1, dec_b1, c1, c1,
                                                           d1n, 64, 16, nullptr, 0, 0);
        small_cell64<<<dim3(3, 12, NB), 256, 0, stream>>>(d1n, 16, 8, hc, c0,
                                                          wd2p, dec_b2, hl, c0);
        tcnn_kernel<<<dim3(36, NB), 256, 0, stream>>>(yp, hl, tcnn_w, tcnn_b, ypn, hcn,
                                                      out + (size_t)t * PIX);
        { unsigned short* tmp = d0c; d0c = d0n; d0n = tmp; }
        { unsigned short* tmp = d1c; d1c = d1n; d1n = tmp; }
        { float* tmp = yp; yp = ypn; ypn = tmp; }
        { float* tmp = hc; hc = hcn; hcn = tmp; }
    }
}

// Round 6
// 1877.148 us; speedup vs baseline: 1.1383x; 1.1383x over previous
//
#include <hip/hip_runtime.h>

// WeatherModel: ConvLSTM encoder-decoder with attention.
// Big ConvLSTM cells + attention e-conv + dec2 via bf16 MFMA implicit GEMM.
// B=4, T_IN=10, T_OUT=5, D=5, M=N=96, H1=64, ATTN=32, SEL=0.

#define PIX  9216
#define NB   4
#define TIN  10
#define TOUT 5
#define ND   5
#define HID  64

typedef __attribute__((ext_vector_type(8))) short bf16x8;
typedef __attribute__((ext_vector_type(4))) float f32x4;

__device__ __forceinline__ float sigmf_(float x) { return 1.0f / (1.0f + __expf(-x)); }
__device__ __forceinline__ float tanhf_(float x) { return 1.0f - 2.0f / (__expf(2.0f * x) + 1.0f); }
__device__ __forceinline__ unsigned short f2bf(float f) {
    unsigned u = __float_as_uint(f);
    unsigned r = u + 0x7FFFu + ((u >> 16) & 1u);
    return (unsigned short)(r >> 16);
}
__device__ __forceinline__ float bf2f(unsigned short u) {
    return __uint_as_float(((unsigned)u) << 16);
}
__device__ __forceinline__ unsigned fmap_(float f) {
    unsigned u = __float_as_uint(f);
    return (u & 0x80000000u) ? ~u : (u | 0x80000000u);
}
__device__ __forceinline__ float funmap_(unsigned v) {
    return __uint_as_float((v & 0x80000000u) ? (v ^ 0x80000000u) : ~v);
}

// ---------------------------------------------------------------------------
// Big ConvLSTM cell, implicit-GEMM MFMA.
// ---------------------------------------------------------------------------
template <int NCH>
__global__ void __launch_bounds__(256, 3)
cell64_mfma(const unsigned short* __restrict__ inP,
            const unsigned short* __restrict__ wP,
            const float* __restrict__ bias,
            const float* cprev, float* cout,
            unsigned short* __restrict__ d1, int d1_coff, int d1_ncg,
            unsigned short* __restrict__ d2, int d2_coff, int d2_ncg)
{
    __shared__ __align__(16) char smem[2][9600];   // [pr 150][4 slots][16B], dbuf
    const int lane = threadIdx.x;
    const int wv   = threadIdx.y;
    const int tid  = wv * 64 + lane;
    const int xh = blockIdx.x, y = blockIdx.y, b = blockIdx.z;
    const int x0 = xh * 48;
    const int l15 = lane & 15, l4 = lane >> 4;
    const int NCG = NCH * 4;

    const int scg  = tid & 3;
    const int spr0 = tid >> 2;

    auto stage = [&](char* buf, int cc) {
#pragma unroll
        for (int i = 0; i < 3; ++i) {
            int pr = spr0 + i * 64;
            if (i == 2 && pr >= 150) break;
            int r = (pr >= 100) ? 2 : (pr >= 50 ? 1 : 0);
            int p = pr - r * 50;
            int gy = y - 1 + r, gx = x0 - 1 + p;
            uint4 v = make_uint4(0u, 0u, 0u, 0u);
            if ((unsigned)gy < 96u && (unsigned)gx < 96u)
                v = *(const uint4*)(inP + (((size_t)(b * NCG + cc * 4 + scg) * 9216
                                            + gy * 96 + gx) << 3));
            int slot = scg ^ ((p >> 1) & 3);
            *(uint4*)(buf + pr * 64 + slot * 16) = v;
        }
    };

    f32x4 acc[4][3] = {};

    stage((char*)smem[0], 0);
    for (int cc = 0; cc < NCH; ++cc) {
        __syncthreads();
        if (cc + 1 < NCH) stage((char*)smem[(cc + 1) & 1], cc + 1);
        const char* buf = (const char*)smem[cc & 1];
#pragma unroll
        for (int ky = 0; ky < 3; ++ky) {
#pragma unroll
            for (int kx = 0; kx < 3; ++kx) {
                const int tap = ky * 3 + kx;
                bf16x8 af[4];
#pragma unroll
                for (int g = 0; g < 4; ++g)
                    af[g] = *(const bf16x8*)(wP
                        + ((size_t)(tap * NCH + cc) * 256 + g * 64 + wv * 16 + l15) * 32 + l4 * 8);
                bf16x8 bk[3];
#pragma unroll
                for (int k = 0; k < 3; ++k) {
                    int p = k * 16 + kx + l15;
                    int slot = l4 ^ ((p >> 1) & 3);
                    bk[k] = *(const bf16x8*)(buf + (ky * 50 + p) * 64 + slot * 16);
                }
#pragma unroll
                for (int g = 0; g < 4; ++g)
#pragma unroll
                    for (int k = 0; k < 3; ++k)
                        acc[g][k] = __builtin_amdgcn_mfma_f32_16x16x32_bf16(
                            af[g], bk[k], acc[g][k], 0, 0, 0);
            }
        }
    }

#pragma unroll
    for (int r = 0; r < 4; ++r) {
        int hc = wv * 16 + l4 * 4 + r;
        float bi = bias[hc], bff = bias[64 + hc];
        float bo = bias[128 + hc], bg = bias[192 + hc];
#pragma unroll
        for (int k = 0; k < 3; ++k) {
            int px = k * 16 + l15;
            int gpix = y * 96 + x0 + px;
            float ii = sigmf_(acc[0][k][r] + bi);
            float ff = sigmf_(acc[1][k][r] + bff);
            float oo = sigmf_(acc[2][k][r] + bo);
            float gg = tanhf_(acc[3][k][r] + bg);
            int cidx = (b * HID + hc) * 9216 + gpix;
            float cn = ff * cprev[cidx] + ii * gg;
            cout[cidx] = cn;
            unsigned short hb = f2bf(oo * tanhf_(cn));
            int ch1 = d1_coff + hc;
            d1[((size_t)(b * d1_ncg + (ch1 >> 3)) * 9216 + gpix) * 8 + (ch1 & 7)] = hb;
            if (d2) {
                int ch2 = d2_coff + hc;
                d2[((size_t)(b * d2_ncg + (ch2 >> 3)) * 9216 + gpix) * 8 + (ch2 & 7)] = hb;
            }
        }
    }
}

__global__ void wpack_kernel(const float* __restrict__ w, unsigned short* __restrict__ wp,
                             int WCIN, int NCH, int coff, int climit)
{
    int idx = blockIdx.x * 256 + threadIdx.x;
    int total = 9 * NCH * 256 * 32;
    if (idx >= total) return;
    int k = idx & 31;
    int oc = (idx >> 5) & 255;
    int rest = idx >> 13;
    int cc = rest % NCH, tap = rest / NCH;
    int c = cc * 32 + k;
    float v = 0.0f;
    if (c < climit) v = w[(oc * WCIN + (c + coff)) * 9 + tap];
    wp[idx] = f2bf(v);
}

// ---------------------------------------------------------------------------
// Small ConvLSTM cell (hidden=1) on 5-ch input: thread per (px, gate).
// ---------------------------------------------------------------------------
__global__ void __launch_bounds__(256)
small_cell5(const float* __restrict__ xs_t,
            const float* __restrict__ hprev, const float* cprev,
            const float* __restrict__ w, const float* __restrict__ bias,
            float* __restrict__ hout, float* cout,
            unsigned short* __restrict__ pk, int ncg)
{
    __shared__ float z[4][64];
    const int pxl = threadIdx.x & 63, gate = threadIdx.x >> 6;
    const int p = blockIdx.x * 64 + pxl, bb = blockIdx.y;
    const int y = p / 96, x = p - y * 96;
    float acc = bias[gate];
#pragma unroll
    for (int cin = 0; cin < 6; ++cin) {
        const float* src = (cin < 5) ? (xs_t + (bb * TIN * ND + cin) * PIX)
                                     : (hprev + bb * PIX);
        const float* wp = w + (gate * 6 + cin) * 9;
#pragma unroll
        for (int ky = 0; ky < 3; ++ky) {
            int gy = y + ky - 1;
            if ((unsigned)gy >= 96u) continue;
#pragma unroll
            for (int kx = 0; kx < 3; ++kx) {
                int gx = x + kx - 1;
                if ((unsigned)gx >= 96u) continue;
                acc = fmaf(wp[ky * 3 + kx], src[gy * 96 + gx], acc);
            }
        }
    }
    z[gate][pxl] = acc;
    __syncthreads();
    if (threadIdx.x < 64) {
        int pp = blockIdx.x * 64 + threadIdx.x;
        int idx = bb * PIX + pp;
        float cn = sigmf_(z[1][threadIdx.x]) * cprev[idx]
                 + sigmf_(z[0][threadIdx.x]) * tanhf_(z[3][threadIdx.x]);
        cout[idx] = cn;
        float h = sigmf_(z[2][threadIdx.x]) * tanhf_(cn);
        hout[idx] = h;
        pk[((size_t)(bb * ncg) * 9216 + pp) * 8] = f2bf(h);
    }
}

// ---------------------------------------------------------------------------
// dec2 layer via MFMA, no LDS. Wave = 16 px (never crosses a row: 96%16==0).
// A = wm[9 taps][2 cc][16 oc][32 cin] (rows 0-3 = gates i,f,o,g; rest zero).
// B = per-lane 16B granules from packed input (cg = cgbase + cc*4 + l4).
// C frag: col=l15=px, row=4*l4+reg -> lanes l4==0 hold all 4 gates in regs.
// Epilogue on those lanes: bias + 1ch fp32 hprev 3x3 conv + LSTM update.
// Grid (144, NB), block 256 = 4 waves, wave w -> px block (blockIdx.x*4+w)*16.
// ---------------------------------------------------------------------------
__global__ void __launch_bounds__(256)
dec2_mfma(const unsigned short* __restrict__ inP, int ncg, int cgbase,
          const float* __restrict__ hprev, const float* cprev,
          const unsigned short* __restrict__ wm,
          const float* __restrict__ w2,      // dec_w2 [4][65][9]
          const float* __restrict__ bias,
          float* __restrict__ hout, float* cout)
{
    const int wv = threadIdx.x >> 6, lane = threadIdx.x & 63;
    const int l15 = lane & 15, l4 = lane >> 4;
    const int b = blockIdx.y;
    const int p0 = (blockIdx.x * 4 + wv) * 16;
    const int y = p0 / 96, xbase = p0 - y * 96;
    const int x = xbase + l15;

    f32x4 acc = {0.f, 0.f, 0.f, 0.f};
#pragma unroll
    for (int ky = 0; ky < 3; ++ky) {
        int gy = y + ky - 1;
        bool oky = (unsigned)gy < 96u;
#pragma unroll
        for (int kx = 0; kx < 3; ++kx) {
            const int tap = ky * 3 + kx;
            int gx = x + kx - 1;
            bool ok = oky && ((unsigned)gx < 96u);
#pragma unroll
            for (int cc = 0; cc < 2; ++cc) {
                bf16x8 a = *(const bf16x8*)(wm + ((size_t)(tap * 2 + cc) * 16 + l15) * 32 + l4 * 8);
                bf16x8 bk = { 0, 0, 0, 0, 0, 0, 0, 0 };
                if (ok)
                    bk = *(const bf16x8*)(inP + ((size_t)(b * ncg + cgbase + cc * 4 + l4) * 9216
                                                 + gy * 96 + gx) * 8);
                acc = __builtin_amdgcn_mfma_f32_16x16x32_bf16(a, bk, acc, 0, 0, 0);
            }
        }
    }

    if (l4 == 0) {
        int px = p0 + l15;
        float aI = acc[0] + bias[0];
        float aF = acc[1] + bias[1];
        float aO = acc[2] + bias[2];
        float aG = acc[3] + bias[3];
        const float* hp = hprev + b * PIX;
#pragma unroll
        for (int ky = 0; ky < 3; ++ky) {
            int gy = y + ky - 1;
            if ((unsigned)gy >= 96u) continue;
#pragma unroll
            for (int kx = 0; kx < 3; ++kx) {
                int gx = x + kx - 1;
                if ((unsigned)gx >= 96u) continue;
                int tap = ky * 3 + kx;
                float hv = hp[gy * 96 + gx];
                aI = fmaf(w2[(0 * 65 + 64) * 9 + tap], hv, aI);
                aF = fmaf(w2[(1 * 65 + 64) * 9 + tap], hv, aF);
                aO = fmaf(w2[(2 * 65 + 64) * 9 + tap], hv, aO);
                aG = fmaf(w2[(3 * 65 + 64) * 9 + tap], hv, aG);
            }
        }
        int idx = b * PIX + px;
        float cn = sigmf_(aF) * cprev[idx] + sigmf_(aI) * tanhf_(aG);
        cout[idx] = cn;
        hout[idx] = sigmf_(aO) * tanhf_(cn);
    }
}

// pack dec_w2 [4 oc][65 cin][9] -> wm [9][2][16][32] bf16 (rows>=4 zero)
__global__ void wd2m_pack_kernel(const float* __restrict__ w, unsigned short* __restrict__ wm)
{
    int idx = blockIdx.x * 256 + threadIdx.x;
    if (idx >= 9 * 2 * 16 * 32) return;
    int k = idx & 31;
    int oc = (idx >> 5) & 15;
    int cc = (idx >> 9) & 1;
    int tap = idx >> 10;
    float v = 0.0f;
    if (oc < 4) v = w[(oc * 65 + cc * 32 + k) * 9 + tap];
    wm[idx] = f2bf(v);
}

// ---------------------------------------------------------------------------
// Attention, MFMA edition.
// ---------------------------------------------------------------------------
__global__ void pack_wi_kernel(const float* __restrict__ wi, unsigned short* __restrict__ wiP)
{
    int idx = blockIdx.x * 256 + threadIdx.x;
    if (idx >= 5120) return;
    int kl = idx & 31, oc = (idx >> 5) & 31, j = idx >> 10;
    int tappos = kl >> 4, ch = kl & 15;
    int tap = 2 * j + tappos;
    float v = 0.0f;
    if (tap < 9 && ch < 10) v = wi[(oc * TIN + ch) * 9 + tap];
    wiP[idx] = f2bf(v);
}

__global__ void hidE_kernel(const float* __restrict__ h0, const float* __restrict__ c0,
                            const float* __restrict__ wh, const float* __restrict__ bh,
                            const float* __restrict__ bi, float* __restrict__ heP)
{
    int idx = blockIdx.x * 256 + threadIdx.x;
    int bb = blockIdx.y;
    int cg = idx & 3, p = idx >> 2;
    int y = p / 96, x = p - y * 96;
    float acc[8];
#pragma unroll
    for (int j = 0; j < 8; ++j) acc[j] = bi[cg * 8 + j] + bh[cg * 8 + j];
#pragma unroll
    for (int cin = 0; cin < 2; ++cin) {
        const float* src = (cin == 0 ? h0 : c0) + bb * PIX;
#pragma unroll
        for (int ky = 0; ky < 3; ++ky) {
            int gy = y + ky - 1;
            if ((unsigned)gy >= 96u) continue;
#pragma unroll
            for (int kx = 0; kx < 3; ++kx) {
                int gx = x + kx - 1;
                if ((unsigned)gx >= 96u) continue;
                float v = src[gy * 96 + gx];
#pragma unroll
                for (int j = 0; j < 8; ++j)
                    acc[j] = fmaf(wh[((cg * 8 + j) * 2 + cin) * 9 + ky * 3 + kx], v, acc[j]);
            }
        }
    }
    float* dst = heP + ((size_t)(bb * PIX) + p) * 32 + cg * 8;
    *(float4*)dst = make_float4(acc[0], acc[1], acc[2], acc[3]);
    *(float4*)(dst + 4) = make_float4(acc[4], acc[5], acc[6], acc[7]);
}

__global__ void __launch_bounds__(256)
attn_e_mfma(const unsigned short* __restrict__ xsp, const unsigned short* __restrict__ wiP,
            const float* __restrict__ heP, unsigned short* __restrict__ eP)
{
    const int lane = threadIdx.x, wvid = threadIdx.y;
    const int tile = blockIdx.x, k = blockIdx.y, bb = blockIdx.z;
    const int l15 = lane & 15, l4 = lane >> 4;

    bf16x8 af[5][2];
#pragma unroll
    for (int j = 0; j < 5; ++j)
#pragma unroll
        for (int m = 0; m < 2; ++m)
            af[j][m] = *(const bf16x8*)(wiP + ((size_t)(j * 32 + m * 16 + l15)) * 32 + l4 * 8);

    const unsigned short* xb = xsp + (size_t)(bb * ND + k) * PIX * 16;
    const int p0 = tile * 256 + wvid * 64;

    f32x4 acc[4][2] = {};
#pragma unroll
    for (int nf = 0; nf < 4; ++nf) {
        int p = p0 + nf * 16 + l15;
        int y = p / 96, x = p - y * 96;
#pragma unroll
        for (int j = 0; j < 5; ++j) {
            int tp = 2 * j + (l4 >> 1);
            bf16x8 bk = { 0, 0, 0, 0, 0, 0, 0, 0 };
            if (tp < 9) {
                int gy = y + tp / 3 - 1, gx = x + tp % 3 - 1;
                if ((unsigned)gy < 96u && (unsigned)gx < 96u)
                    bk = *(const bf16x8*)(xb + ((size_t)(gy * 96 + gx)) * 16 + (l4 & 1) * 8);
            }
            acc[nf][0] = __builtin_amdgcn_mfma_f32_16x16x32_bf16(af[j][0], bk, acc[nf][0], 0, 0, 0);
            acc[nf][1] = __builtin_amdgcn_mfma_f32_16x16x32_bf16(af[j][1], bk, acc[nf][1], 0, 0, 0);
        }
    }

#pragma unroll
    for (int nf = 0; nf < 4; ++nf) {
        int p = p0 + nf * 16 + l15;
#pragma unroll
        for (int m = 0; m < 2; ++m) {
            const float4 he = *(const float4*)(heP + ((size_t)(bb * PIX) + p) * 32 + m * 16 + l4 * 4);
            ushort4 o;
            o.x = f2bf(tanhf_(acc[nf][m][0] + he.x));
            o.y = f2bf(tanhf_(acc[nf][m][1] + he.y));
            o.z = f2bf(tanhf_(acc[nf][m][2] + he.z));
            o.w = f2bf(tanhf_(acc[nf][m][3] + he.w));
            *(ushort4*)(eP + ((size_t)(bb * ND + k) * PIX + p) * 32 + m * 16 + l4 * 4) = o;
        }
    }
}

__global__ void __launch_bounds__(256)
attn_alpha(const unsigned short* __restrict__ eP, const float* __restrict__ wvv,
           const float* __restrict__ bv, float* __restrict__ alpha,
           unsigned* __restrict__ msl)
{
    int p = blockIdx.x * 256 + threadIdx.x;
    int k = blockIdx.y, bb = blockIdx.z;
    int y = p / 96, x = p - y * 96;
    const unsigned short* eb = eP + (size_t)(bb * ND + k) * PIX * 32;
    float acc = bv[0];
#pragma unroll
    for (int ky = 0; ky < 3; ++ky) {
        int gy = y + ky - 1;
        if ((unsigned)gy >= 96u) continue;
#pragma unroll
        for (int kx = 0; kx < 3; ++kx) {
            int gx = x + kx - 1;
            if ((unsigned)gx >= 96u) continue;
            int tap = ky * 3 + kx;
            const unsigned short* ee = eb + ((size_t)(gy * 96 + gx)) * 32;
#pragma unroll
            for (int cg = 0; cg < 4; ++cg) {
                bf16x8 ev = *(const bf16x8*)(ee + cg * 8);
#pragma unroll
                for (int jj = 0; jj < 8; ++jj)
                    acc = fmaf(wvv[(cg * 8 + jj) * 9 + tap], bf2f((unsigned short)ev[jj]), acc);
            }
        }
    }
    alpha[(size_t)(bb * ND + k) * PIX + p] = acc;

    __shared__ float s[256];
    s[threadIdx.x] = acc;
    __syncthreads();
    for (int st = 128; st > 0; st >>= 1) {
        if (threadIdx.x < st) s[threadIdx.x] = fmaxf(s[threadIdx.x], s[threadIdx.x + st]);
        __syncthreads();
    }
    if (threadIdx.x == 0) atomicMax(msl, fmap_(s[0]));
}

__global__ void scale_pack_kernel(float* __restrict__ xs, unsigned short* __restrict__ xsp,
                                  const float* __restrict__ alpha,
                                  const unsigned* __restrict__ msl)
{
    int idx = blockIdx.x * 256 + threadIdx.x;
    int p = idx % PIX;
    int q = idx / PIX;
    int d = q % ND, bb = q / ND;
    float mval = funmap_(msl[0]);
    float w = __expf(alpha[idx] - mval);
    unsigned short tmp[16];
#pragma unroll
    for (int t = 0; t < TIN; ++t) {
        size_t xi = ((size_t)(bb * TIN + t) * ND + d) * PIX + p;
        float v = xs[xi] * w;
        xs[xi] = v;
        tmp[t] = f2bf(v);
    }
#pragma unroll
    for (int t = TIN; t < 16; ++t) tmp[t] = 0;
    uint4* dst = (uint4*)(xsp + (size_t)idx * 16);
    dst[0] = *(uint4*)&tmp[0];
    dst[1] = *(uint4*)&tmp[8];
}

__global__ void pack_xsp_kernel(const float* __restrict__ x, unsigned short* __restrict__ xsp)
{
    int idx = blockIdx.x * 256 + threadIdx.x;
    int p = idx % PIX;
    int q = idx / PIX;
    int d = q % ND, bb = q / ND;
    unsigned short tmp[16];
#pragma unroll
    for (int t = 0; t < TIN; ++t)
        tmp[t] = f2bf(x[((size_t)(bb * TIN + t) * ND + d) * PIX + p]);
#pragma unroll
    for (int t = TIN; t < 16; ++t) tmp[t] = 0;
    uint4* dst = (uint4*)(xsp + (size_t)idx * 16);
    dst[0] = *(uint4*)&tmp[0];
    dst[1] = *(uint4*)&tmp[8];
}

// ---------------------------------------------------------------------------
__global__ void tcnn_kernel(const float* __restrict__ yprev, const float* __restrict__ hl,
                            const float* __restrict__ tw, const float* __restrict__ tb,
                            float* __restrict__ ynext, float* __restrict__ hcarry,
                            float* __restrict__ outp)
{
    int p = blockIdx.x * 256 + threadIdx.x;
    int bb = blockIdx.y;
    float acc = tb[0];
#pragma unroll
    for (int cc = 0; cc < TIN; ++cc)
        acc = fmaf(tw[cc], yprev[(bb * TIN + cc) * PIX + p], acc);
    float hv = hl[bb * PIX + p];
    acc = fmaf(tw[TIN], hv, acc);
    float o = fmaxf(acc, 0.0f);
    outp[bb * TOUT * PIX + p] = o;
#pragma unroll
    for (int cc = 0; cc < TIN - 1; ++cc)
        ynext[(bb * TIN + cc) * PIX + p] = yprev[(bb * TIN + cc + 1) * PIX + p];
    ynext[(bb * TIN + 9) * PIX + p] = hv;
    hcarry[bb * PIX + p] = o;
}

__global__ void slice_y_kernel(const float* __restrict__ x, float* __restrict__ yp)
{
    int idx = blockIdx.x * 256 + threadIdx.x;
    int p = idx % PIX;
    int q = idx / PIX;
    yp[idx] = x[(size_t)(q * ND + 0) * PIX + p];
}

// ---------------------------------------------------------------------------
extern "C" void kernel_launch(void* const* d_in, const int* in_sizes, int n_in,
                              void* d_out, int out_size, void* d_ws, size_t ws_size,
                              hipStream_t stream)
{
    const float* x       = (const float*)d_in[0];
    const float* enc_w0  = (const float*)d_in[1];
    const float* enc_b0  = (const float*)d_in[2];
    const float* enc_w1  = (const float*)d_in[3];
    const float* enc_b1  = (const float*)d_in[4];
    const float* enc_w2  = (const float*)d_in[5];
    const float* enc_b2  = (const float*)d_in[6];
    const float* dec_w0  = (const float*)d_in[7];
    const float* dec_b0  = (const float*)d_in[8];
    const float* dec_w1  = (const float*)d_in[9];
    const float* dec_b1  = (const float*)d_in[10];
    const float* dec_w2  = (const float*)d_in[11];
    const float* dec_b2  = (const float*)d_in[12];
    const float* attn_wi = (const float*)d_in[13];
    const float* attn_bi = (const float*)d_in[14];
    const float* attn_wh = (const float*)d_in[15];
    const float* attn_bh = (const float*)d_in[16];
    const float* attn_wv = (const float*)d_in[17];
    const float* attn_bv = (const float*)d_in[18];
    const float* tcnn_w  = (const float*)d_in[19];
    const float* tcnn_b  = (const float*)d_in[20];
    float* out = (float*)d_out;

    char* cur = (char*)d_ws;
    auto alloc = [&](size_t bytes) { char* p = cur; cur += (bytes + 255) & ~(size_t)255; return p; };
    float* xs   = (float*)alloc((size_t)NB * TIN * ND * PIX * 4);
    float* h0a  = (float*)alloc(NB * PIX * 4);
    float* h0b  = (float*)alloc(NB * PIX * 4);
    float* c0   = (float*)alloc(NB * PIX * 4);
    float* hl   = (float*)alloc(NB * PIX * 4);
    float* c1   = (float*)alloc((size_t)NB * HID * PIX * 4);
    float* c2   = (float*)alloc((size_t)NB * HID * PIX * 4);
    float* alp  = (float*)alloc((size_t)NB * ND * PIX * 4);
    float* ypa  = (float*)alloc((size_t)NB * TIN * PIX * 4);
    float* ypb  = (float*)alloc((size_t)NB * TIN * PIX * 4);
    unsigned* mslot = (unsigned*)alloc(256);
    const size_t IN1_B = (size_t)NB * 12 * PIX * 8 * 2;
    const size_t IN2_B = (size_t)NB * 16 * PIX * 8 * 2;
    unsigned short* In1a = (unsigned short*)alloc(IN1_B);
    unsigned short* In1b = (unsigned short*)alloc(IN1_B);
    unsigned short* In2a = (unsigned short*)alloc(IN2_B);
    unsigned short* In2b = (unsigned short*)alloc(IN2_B);
    unsigned short* wpe1 = (unsigned short*)alloc((size_t)9 * 3 * 256 * 32 * 2);
    unsigned short* wpe2 = (unsigned short*)alloc((size_t)9 * 4 * 256 * 32 * 2);
    unsigned short* wpd0 = (unsigned short*)alloc((size_t)9 * 2 * 256 * 32 * 2);
    unsigned short* wpd1 = (unsigned short*)alloc((size_t)9 * 4 * 256 * 32 * 2);
    unsigned short* wd2m = (unsigned short*)alloc((size_t)9 * 2 * 16 * 32 * 2);
    unsigned short* xsp  = (unsigned short*)alloc((size_t)NB * ND * PIX * 16 * 2);
    unsigned short* wiP  = (unsigned short*)alloc(5120 * 2);
    float* heP = (float*)alloc((size_t)NB * PIX * 32 * 4);
    unsigned short* eP = (unsigned short*)alloc((size_t)NB * ND * PIX * 32 * 2);

    hipMemcpyAsync(xs, x, (size_t)NB * TIN * ND * PIX * 4, hipMemcpyDeviceToDevice, stream);
    hipMemsetAsync(h0a, 0, NB * PIX * 4, stream);
    hipMemsetAsync(c0,  0, NB * PIX * 4, stream);
    hipMemsetAsync(c1,  0, (size_t)NB * HID * PIX * 4, stream);
    hipMemsetAsync(c2,  0, (size_t)NB * HID * PIX * 4, stream);
    hipMemsetAsync(In1a, 0, IN1_B, stream);
    hipMemsetAsync(In1b, 0, IN1_B, stream);
    hipMemsetAsync(In2a, 0, IN2_B, stream);
    hipMemsetAsync(In2b, 0, IN2_B, stream);
    hipMemsetAsync(mslot, 0, 256, stream);
    slice_y_kernel<<<dim3(1440), 256, 0, stream>>>(x, ypa);

    wpack_kernel<<<dim3(864),  256, 0, stream>>>(enc_w1, wpe1, 65, 3, 0, 65);
    wpack_kernel<<<dim3(1152), 256, 0, stream>>>(enc_w2, wpe2, 128, 4, 0, 128);
    wpack_kernel<<<dim3(576),  256, 0, stream>>>(dec_w0, wpd0, 65, 2, 1, 64);
    wpack_kernel<<<dim3(1152), 256, 0, stream>>>(dec_w1, wpd1, 128, 4, 0, 128);
    wd2m_pack_kernel<<<dim3(36), 256, 0, stream>>>(dec_w2, wd2m);
    pack_wi_kernel<<<dim3(20), 256, 0, stream>>>(attn_wi, wiP);
    pack_xsp_kernel<<<dim3(720), 256, 0, stream>>>(x, xsp);

    dim3 big_grid(2, 96, NB), big_block(64, 4);
    dim3 attn_block(64, 4);
    float *h0 = h0a, *h0n = h0b;
    unsigned short *i1c = In1a, *i1n = In1b, *i2c = In2a, *i2n = In2b;

    // ---------------- encoder ----------------
    for (int t = 0; t < TIN; ++t) {
        hidE_kernel<<<dim3(144, NB), 256, 0, stream>>>(h0, c0, attn_wh, attn_bh, attn_bi, heP);
        attn_e_mfma<<<dim3(36, ND, NB), attn_block, 0, stream>>>(xsp, wiP, heP, eP);
        attn_alpha<<<dim3(36, ND, NB), 256, 0, stream>>>(eP, attn_wv, attn_bv, alp, mslot + t);
        scale_pack_kernel<<<dim3(720), 256, 0, stream>>>(xs, xsp, alp, mslot + t);

        small_cell5<<<dim3(144, NB), 256, 0, stream>>>(xs + (size_t)t * ND * PIX, h0, c0,
                                                       enc_w0, enc_b0, h0n, c0, i1c, 12);
        { float* tmp = h0; h0 = h0n; h0n = tmp; }

        unsigned short* e1d1 = (t < TIN - 1) ? i1n : In2a;
        int e1o = (t < TIN - 1) ? 1 : 64;
        int e1n = (t < TIN - 1) ? 12 : 16;
        cell64_mfma<3><<<big_grid, big_block, 0, stream>>>(i1c, wpe1, enc_b1, c1, c1,
                                                           e1d1, e1o, e1n, i2c, 0, 16);
        unsigned short* e2d1 = (t < TIN - 1) ? i2n : In1a;
        int e2o = (t < TIN - 1) ? 64 : 0;
        int e2n = (t < TIN - 1) ? 16 : 8;
        cell64_mfma<4><<<big_grid, big_block, 0, stream>>>(i2c, wpe2, enc_b2, c2, c2,
                                                           e2d1, e2o, e2n, nullptr, 0, 0);
        { unsigned short* tmp = i1c; i1c = i1n; i1n = tmp; }
        { unsigned short* tmp = i2c; i2c = i2n; i2n = tmp; }
    }

    // ---------------- decoder ----------------
    unsigned short *d0c = In1a, *d0n = In1b, *d1c = In2a, *d1n = In2b;
    float *yp = ypa, *ypn = ypb, *hc = h0, *hcn = h0n;
    for (int t = 0; t < TOUT; ++t) {
        cell64_mfma<2><<<big_grid, big_block, 0, stream>>>(d0c, wpd0, dec_b0, c2, c2,
                                                           d0n, 0, 8, d1c, 0, 16);
        cell64_mfma<4><<<big_grid, big_block, 0, stream>>>(d1c, wpd1, dec_b1, c1, c1,
                                                           d1n, 64, 16, nullptr, 0, 0);
        dec2_mfma<<<dim3(144, NB), 256, 0, stream>>>(d1n, 16, 8, hc, c0,
                                                     wd2m, dec_w2, dec_b2, hl, c0);
        tcnn_kernel<<<dim3(36, NB), 256, 0, stream>>>(yp, hl, tcnn_w, tcnn_b, ypn, hcn,
                                                      out + (size_t)t * PIX);
        { unsigned short* tmp = d0c; d0c = d0n; d0n = tmp; }
        { unsigned short* tmp = d1c; d1c = d1n; d1n = tmp; }
        { float* tmp = yp; yp = ypn; ypn = tmp; }
        { float* tmp = hc; hc = hcn; hcn = tmp; }
    }
}